// Round 10
// baseline (389.679 us; speedup 1.0000x reference)
//
#include <hip/hip_runtime.h>

// Pool255: out = (1/8) * sum of 8 directional cumulative-max pools.
// x: [8,256,128,128] fp32. 2048 blocks (2 waves), one image per block.
//
// R10 structure — half-image ownership, register-resident partials:
//   wave0 owns real rows 0..63, wave1 owns real rows 64..127.
//   Phase A: each wave runs the TD-style 4-dir sweep over ITS rows in its
//     own view (wave0: identity; wave1: 180-rotated view, in which the BU
//     dirs {(1,0),(1,1),(1,-1),(0,1)} become the TD dirs) -- identical code.
//     The per-pixel 4-dir sum is packed fp16x2 into 64 VGPRs (S0..S7,
//     static indexing). Final recurrence state {v,d,a} -> 3 KB LDS carry.
//   lgkm-only barrier.
//   Phase B: each wave continues the PARTNER's logical sweep over its own
//     rows (opposite view, recurrences seeded from partner's carry),
//     combines with its stored phase-A sums (ds_bpermute lane 63-l mirror +
//     component swap), NT-stores out.
// No 32 KB LDS buffer -> occupancy is VGPR-bound (~4 waves/SIMD vs 2).
// Row recurrences: vertical = register max; diag/anti = DPP wave_shr/shl:1
// (NEGF boundary via `old`); row scan = 6-step DPP prefix-max.

#define NPIX 16384
#define NEGF (-3.402823466e38f)

typedef __fp16 half2v __attribute__((ext_vector_type(2)));

// dst[l] = src[l -/+ 1]; invalid lanes get `oldv`.
template <int CTRL>
__device__ __forceinline__ float dpp_movf(float oldv, float src) {
  return __int_as_float(__builtin_amdgcn_update_dpp(
      __float_as_int(oldv), __float_as_int(src), CTRL, 0xf, 0xf, false));
}
#define WAVE_SHR1 0x138  // lane l reads lane l-1 (lane 0 -> old)
#define WAVE_SHL1 0x130  // lane l reads lane l+1 (lane 63 -> old)

// y = max(y, dpp_move(y)) ; masked/invalid lanes keep old=y (no-op)
#define DPP_MAXSTEP(y, ctrl, rmask)                                          \
  y = fmaxf(y, __int_as_float(__builtin_amdgcn_update_dpp(                   \
                 __float_as_int(y), __float_as_int(y), ctrl, rmask, 0xf,     \
                 false)))

// Barrier draining only LDS (lgkm) — global prefetches stay in flight.
__device__ __forceinline__ void lds_barrier() {
  asm volatile("s_waitcnt lgkmcnt(0)\n\ts_barrier" ::: "memory");
}

struct Sweep {
  float v0, v1, d0, d1, a0, a1;
};

// One view-row step of the TD-style 4-dir recurrence set; yields the
// per-pixel 4-dir sum (p0 = view col 2l, p1 = view col 2l+1).
template <bool MIR>
__device__ __forceinline__ void row_step(const float2 xv, Sweep& s,
                                         float& p0, float& p1) {
  const float x0 = MIR ? xv.y : xv.x;
  const float x1 = MIR ? xv.x : xv.y;
  s.v0 = fmaxf(s.v0, x0);
  s.v1 = fmaxf(s.v1, x1);
  // diag: D[c] = max(x[c], Dprev[c-1])
  const float pd = dpp_movf<WAVE_SHR1>(NEGF, s.d1);
  const float nd0 = fmaxf(x0, pd);
  const float nd1 = fmaxf(x1, s.d0);
  s.d0 = nd0; s.d1 = nd1;
  // anti: A[c] = max(x[c], Aprev[c+1])
  const float pa = dpp_movf<WAVE_SHL1>(NEGF, s.a0);
  const float na1 = fmaxf(x1, pa);
  const float na0 = fmaxf(x0, s.a1);
  s.a0 = na0; s.a1 = na1;
  // row inclusive prefix-max (DPP scan)
  float y = fmaxf(x0, x1);
  DPP_MAXSTEP(y, 0x111, 0xf);  // row_shr:1
  DPP_MAXSTEP(y, 0x112, 0xf);  // row_shr:2
  DPP_MAXSTEP(y, 0x114, 0xf);  // row_shr:4
  DPP_MAXSTEP(y, 0x118, 0xf);  // row_shr:8
  DPP_MAXSTEP(y, 0x142, 0xa);  // row_bcast15 -> rows 1,3
  DPP_MAXSTEP(y, 0x143, 0xc);  // row_bcast31 -> rows 2,3
  const float ex = dpp_movf<WAVE_SHR1>(NEGF, y);
  const float sc0 = fmaxf(ex, x0);
  p0 = (s.v0 + s.d0) + (s.a0 + sc0);
  p1 = (s.v1 + s.d1) + (s.a1 + y);
}

// Phase A sub-block: 8 view-rows, store packed sums into S.
template <bool MIR>
__device__ __forceinline__ void subA(unsigned (&S)[8], const int tb,
                                     const float* __restrict__ base,
                                     float2 (&G)[8], Sweep& s) {
  constexpr int RS = MIR ? -128 : 128;
#pragma unroll
  for (int k = 0; k < 8; ++k) {
    const float2 xv = G[k];
    G[k] = *(const float2*)(base + (ptrdiff_t)(tb + 8 + k) * RS);
    float p0, p1;
    row_step<MIR>(xv, s, p0, p1);
    const half2v h = __builtin_amdgcn_cvt_pkrtz(p0, p1);
    S[k] = __builtin_bit_cast(unsigned, h);
  }
}

// Phase B sub-block: 8 view-rows (view rows 64..127 of the OPPOSITE view),
// combine with mirrored stored sums, NT-store final output.
template <bool MIR>
__device__ __forceinline__ void subB(unsigned (&S)[8], const int tb,
                                     const float* __restrict__ base,
                                     float* __restrict__ oim, const int off,
                                     const int addr_rev, float2 (&G)[8],
                                     Sweep& s) {
  constexpr int RS = MIR ? -128 : 128;
#pragma unroll
  for (int k = 0; k < 8; ++k) {
    const int t = tb + k;
    const float2 xv = G[k];
    const int tp = (t + 8 < 128) ? (t + 8) : 127;  // clamp (uniform)
    G[k] = *(const float2*)(base + (ptrdiff_t)tp * RS);
    // partner-lane (63-l) phase-A sum for this real pixel pair
    const unsigned q =
        (unsigned)__builtin_amdgcn_ds_bpermute(addr_rev, (int)S[7 - k]);
    float p0, p1;
    row_step<MIR>(xv, s, p0, p1);
    const half2v hq = __builtin_bit_cast(half2v, q);
    const float o0 = (p0 + (float)hq.y) * 0.125f;  // view col 2l   <- src p1
    const float o1 = (p1 + (float)hq.x) * 0.125f;  // view col 2l+1 <- src p0
    const int row = MIR ? 127 - t : t;
    const float2 ov = MIR ? make_float2(o1, o0) : make_float2(o0, o1);
    __builtin_nontemporal_store(
        __builtin_bit_cast(unsigned long long, ov),
        (unsigned long long*)(oim + (row << 7) + off));
  }
}

template <bool MIRA>
__device__ __forceinline__ void wave_run(const float* __restrict__ xim,
                                         float* __restrict__ oim,
                                         float2 (*carry)[3][64], const int l) {
  constexpr bool MIRB = !MIRA;
  constexpr int wid = MIRA ? 1 : 0;
  Sweep s{NEGF, NEGF, NEGF, NEGF, NEGF, NEGF};
  unsigned S0[8], S1[8], S2[8], S3[8], S4[8], S5[8], S6[8], S7[8];
  float2 G[8];

  // ---- phase A: own half, own view, rows 0..63 ----
  {
    constexpr int RS = MIRA ? -128 : 128;
    const int off = MIRA ? (63 - l) * 2 : l * 2;
    const float* __restrict__ base = xim + off + (MIRA ? 127 * 128 : 0);
#pragma unroll
    for (int k = 0; k < 8; ++k)
      G[k] = *(const float2*)(base + (ptrdiff_t)k * RS);
    subA<MIRA>(S0, 0, base, G, s);
    subA<MIRA>(S1, 8, base, G, s);
    subA<MIRA>(S2, 16, base, G, s);
    subA<MIRA>(S3, 24, base, G, s);
    subA<MIRA>(S4, 32, base, G, s);
    subA<MIRA>(S5, 40, base, G, s);
    subA<MIRA>(S6, 48, base, G, s);
    subA<MIRA>(S7, 56, base, G, s);
    carry[wid][0][l] = make_float2(s.v0, s.v1);
    carry[wid][1][l] = make_float2(s.d0, s.d1);
    carry[wid][2][l] = make_float2(s.a0, s.a1);
  }

  lds_barrier();  // carries visible; x prefetches stay in flight

  // ---- phase B: own half, OPPOSITE view rows 64..127, seeded ----
  {
    constexpr int RS = MIRB ? -128 : 128;
    const int off = MIRB ? (63 - l) * 2 : l * 2;
    const float* __restrict__ base = xim + off + (MIRB ? 127 * 128 : 0);
    const float2 cv = carry[1 - wid][0][l];
    const float2 cd = carry[1 - wid][1][l];
    const float2 ca = carry[1 - wid][2][l];
    s.v0 = cv.x; s.v1 = cv.y;
    s.d0 = cd.x; s.d1 = cd.y;
    s.a0 = ca.x; s.a1 = ca.y;
    const int addr_rev = (63 - l) * 4;
#pragma unroll
    for (int k = 0; k < 8; ++k)
      G[k] = *(const float2*)(base + (ptrdiff_t)(64 + k) * RS);
    subB<MIRB>(S7, 64, base, oim, off, addr_rev, G, s);
    subB<MIRB>(S6, 72, base, oim, off, addr_rev, G, s);
    subB<MIRB>(S5, 80, base, oim, off, addr_rev, G, s);
    subB<MIRB>(S4, 88, base, oim, off, addr_rev, G, s);
    subB<MIRB>(S3, 96, base, oim, off, addr_rev, G, s);
    subB<MIRB>(S2, 104, base, oim, off, addr_rev, G, s);
    subB<MIRB>(S1, 112, base, oim, off, addr_rev, G, s);
    subB<MIRB>(S0, 120, base, oim, off, addr_rev, G, s);
  }
}

__global__ __launch_bounds__(128, 4) void pool255_half(
    const float* __restrict__ x, float* __restrict__ out) {
  __shared__ float2 carry[2][3][64];  // 3 KB
  const int img = blockIdx.x;
  const float* __restrict__ xim = x + (size_t)img * NPIX;
  float* __restrict__ oim = out + (size_t)img * NPIX;
  const int l = threadIdx.x & 63;
  if (threadIdx.x < 64)
    wave_run<false>(xim, oim, carry, l);  // rows 0..63, TD first
  else
    wave_run<true>(xim, oim, carry, l);   // rows 64..127, BU first
}

extern "C" void kernel_launch(void* const* d_in, const int* in_sizes, int n_in,
                              void* d_out, int out_size, void* d_ws,
                              size_t ws_size, hipStream_t stream) {
  const float* x = (const float*)d_in[0];
  float* out = (float*)d_out;
  const int n_img = in_sizes[0] / NPIX;  // 8*256 = 2048
  pool255_half<<<n_img, 128, 0, stream>>>(x, out);
}

// Round 11
// 116.211 us; speedup vs baseline: 3.3532x; 3.3532x over previous
//
#include <hip/hip_runtime.h>

// Pool255: out = (1/8) * sum of 8 directional cumulative-max pools.
// x: [8,256,128,128] fp32. 2048 blocks (2 waves), one image per block.
//
// Half-image ownership, register-resident partials (R10 structure):
//   wave0 owns real rows 0..63, wave1 owns real rows 64..127.
//   Phase A: each wave runs the TD-style 4-dir sweep over ITS rows in its
//     own view (wave0: identity; wave1: 180-rotated view) -- identical code.
//     Per-pixel 4-dir sums packed fp16x2 into 64 VGPRs (S0..S7, static
//     indexing). Final recurrence state {v,d,a} -> 3 KB LDS carry.
//   lgkm-only barrier (global prefetches stay in flight).
//   Phase B: each wave continues the PARTNER's logical sweep over its own
//     rows (opposite view, seeded from partner's carry), combines with its
//     stored phase-A sums (ds_bpermute 63-l mirror + component swap),
//     NT-stores out. Phase-B x re-reads hit L2.
//
// R11 fix vs R10: NO min-waves launch bound (it forced VGPR=64 -> massive
// scratch spills, 390us). Depth-4 prefetch ring (G[4], 8 VGPR) to keep total
// ~110 VGPR < 128 step -> 16 waves/CU without spilling.

#define NPIX 16384
#define NEGF (-3.402823466e38f)

typedef __fp16 half2v __attribute__((ext_vector_type(2)));

// dst[l] = src[l -/+ 1]; invalid lanes get `oldv`.
template <int CTRL>
__device__ __forceinline__ float dpp_movf(float oldv, float src) {
  return __int_as_float(__builtin_amdgcn_update_dpp(
      __float_as_int(oldv), __float_as_int(src), CTRL, 0xf, 0xf, false));
}
#define WAVE_SHR1 0x138  // lane l reads lane l-1 (lane 0 -> old)
#define WAVE_SHL1 0x130  // lane l reads lane l+1 (lane 63 -> old)

// y = max(y, dpp_move(y)) ; masked/invalid lanes keep old=y (no-op)
#define DPP_MAXSTEP(y, ctrl, rmask)                                          \
  y = fmaxf(y, __int_as_float(__builtin_amdgcn_update_dpp(                   \
                 __float_as_int(y), __float_as_int(y), ctrl, rmask, 0xf,     \
                 false)))

// Barrier draining only LDS (lgkm) — global prefetches stay in flight.
__device__ __forceinline__ void lds_barrier() {
  asm volatile("s_waitcnt lgkmcnt(0)\n\ts_barrier" ::: "memory");
}

struct Sweep {
  float v0, v1, d0, d1, a0, a1;
};

// One view-row step of the TD-style 4-dir recurrence set; yields the
// per-pixel 4-dir sum (p0 = view col 2l, p1 = view col 2l+1).
template <bool MIR>
__device__ __forceinline__ void row_step(const float2 xv, Sweep& s,
                                         float& p0, float& p1) {
  const float x0 = MIR ? xv.y : xv.x;
  const float x1 = MIR ? xv.x : xv.y;
  s.v0 = fmaxf(s.v0, x0);
  s.v1 = fmaxf(s.v1, x1);
  // diag: D[c] = max(x[c], Dprev[c-1])
  const float pd = dpp_movf<WAVE_SHR1>(NEGF, s.d1);
  const float nd0 = fmaxf(x0, pd);
  const float nd1 = fmaxf(x1, s.d0);
  s.d0 = nd0; s.d1 = nd1;
  // anti: A[c] = max(x[c], Aprev[c+1])
  const float pa = dpp_movf<WAVE_SHL1>(NEGF, s.a0);
  const float na1 = fmaxf(x1, pa);
  const float na0 = fmaxf(x0, s.a1);
  s.a0 = na0; s.a1 = na1;
  // row inclusive prefix-max (DPP scan)
  float y = fmaxf(x0, x1);
  DPP_MAXSTEP(y, 0x111, 0xf);  // row_shr:1
  DPP_MAXSTEP(y, 0x112, 0xf);  // row_shr:2
  DPP_MAXSTEP(y, 0x114, 0xf);  // row_shr:4
  DPP_MAXSTEP(y, 0x118, 0xf);  // row_shr:8
  DPP_MAXSTEP(y, 0x142, 0xa);  // row_bcast15 -> rows 1,3
  DPP_MAXSTEP(y, 0x143, 0xc);  // row_bcast31 -> rows 2,3
  const float ex = dpp_movf<WAVE_SHR1>(NEGF, y);
  const float sc0 = fmaxf(ex, x0);
  p0 = (s.v0 + s.d0) + (s.a0 + sc0);
  p1 = (s.v1 + s.d1) + (s.a1 + y);
}

// Phase A sub-block: 8 view-rows, store packed sums into S. Ring depth 4.
template <bool MIR>
__device__ __forceinline__ void subA(unsigned (&S)[8], const int tb,
                                     const float* __restrict__ base,
                                     float2 (&G)[4], Sweep& s) {
  constexpr int RS = MIR ? -128 : 128;
#pragma unroll
  for (int k = 0; k < 8; ++k) {
    const float2 xv = G[k & 3];
    G[k & 3] = *(const float2*)(base + (ptrdiff_t)(tb + k + 4) * RS);
    float p0, p1;
    row_step<MIR>(xv, s, p0, p1);
    const half2v h = __builtin_amdgcn_cvt_pkrtz(p0, p1);
    S[k] = __builtin_bit_cast(unsigned, h);
  }
}

// Phase B sub-block: 8 view-rows (rows 64..127 of the OPPOSITE view),
// combine with mirrored stored sums, NT-store final output.
template <bool MIR>
__device__ __forceinline__ void subB(unsigned (&S)[8], const int tb,
                                     const float* __restrict__ base,
                                     float* __restrict__ oim, const int off,
                                     const int addr_rev, float2 (&G)[4],
                                     Sweep& s) {
  constexpr int RS = MIR ? -128 : 128;
#pragma unroll
  for (int k = 0; k < 8; ++k) {
    const int t = tb + k;
    const float2 xv = G[k & 3];
    const int tp = (t + 4 < 128) ? (t + 4) : 127;  // clamp (uniform)
    G[k & 3] = *(const float2*)(base + (ptrdiff_t)tp * RS);
    // partner-lane (63-l) phase-A sum for this real pixel pair
    const unsigned q =
        (unsigned)__builtin_amdgcn_ds_bpermute(addr_rev, (int)S[7 - k]);
    float p0, p1;
    row_step<MIR>(xv, s, p0, p1);
    const half2v hq = __builtin_bit_cast(half2v, q);
    const float o0 = (p0 + (float)hq.y) * 0.125f;  // view col 2l   <- src p1
    const float o1 = (p1 + (float)hq.x) * 0.125f;  // view col 2l+1 <- src p0
    const int row = MIR ? 127 - t : t;
    const float2 ov = MIR ? make_float2(o1, o0) : make_float2(o0, o1);
    __builtin_nontemporal_store(
        __builtin_bit_cast(unsigned long long, ov),
        (unsigned long long*)(oim + (row << 7) + off));
  }
}

template <bool MIRA>
__device__ __forceinline__ void wave_run(const float* __restrict__ xim,
                                         float* __restrict__ oim,
                                         float2 (*carry)[3][64], const int l) {
  constexpr bool MIRB = !MIRA;
  constexpr int wid = MIRA ? 1 : 0;
  Sweep s{NEGF, NEGF, NEGF, NEGF, NEGF, NEGF};
  unsigned S0[8], S1[8], S2[8], S3[8], S4[8], S5[8], S6[8], S7[8];
  float2 G[4];

  // ---- phase A: own half, own view, rows 0..63 ----
  {
    constexpr int RS = MIRA ? -128 : 128;
    const int off = MIRA ? (63 - l) * 2 : l * 2;
    const float* __restrict__ base = xim + off + (MIRA ? 127 * 128 : 0);
#pragma unroll
    for (int k = 0; k < 4; ++k)
      G[k] = *(const float2*)(base + (ptrdiff_t)k * RS);
    subA<MIRA>(S0, 0, base, G, s);
    subA<MIRA>(S1, 8, base, G, s);
    subA<MIRA>(S2, 16, base, G, s);
    subA<MIRA>(S3, 24, base, G, s);
    subA<MIRA>(S4, 32, base, G, s);
    subA<MIRA>(S5, 40, base, G, s);
    subA<MIRA>(S6, 48, base, G, s);
    subA<MIRA>(S7, 56, base, G, s);
    carry[wid][0][l] = make_float2(s.v0, s.v1);
    carry[wid][1][l] = make_float2(s.d0, s.d1);
    carry[wid][2][l] = make_float2(s.a0, s.a1);
  }

  lds_barrier();  // carries visible; x prefetches stay in flight

  // ---- phase B: own half, OPPOSITE view rows 64..127, seeded ----
  {
    constexpr int RS = MIRB ? -128 : 128;
    const int off = MIRB ? (63 - l) * 2 : l * 2;
    const float* __restrict__ base = xim + off + (MIRB ? 127 * 128 : 0);
    const float2 cv = carry[1 - wid][0][l];
    const float2 cd = carry[1 - wid][1][l];
    const float2 ca = carry[1 - wid][2][l];
    s.v0 = cv.x; s.v1 = cv.y;
    s.d0 = cd.x; s.d1 = cd.y;
    s.a0 = ca.x; s.a1 = ca.y;
    const int addr_rev = (63 - l) * 4;
#pragma unroll
    for (int k = 0; k < 4; ++k)
      G[k] = *(const float2*)(base + (ptrdiff_t)(64 + k) * RS);
    subB<MIRB>(S7, 64, base, oim, off, addr_rev, G, s);
    subB<MIRB>(S6, 72, base, oim, off, addr_rev, G, s);
    subB<MIRB>(S5, 80, base, oim, off, addr_rev, G, s);
    subB<MIRB>(S4, 88, base, oim, off, addr_rev, G, s);
    subB<MIRB>(S3, 96, base, oim, off, addr_rev, G, s);
    subB<MIRB>(S2, 104, base, oim, off, addr_rev, G, s);
    subB<MIRB>(S1, 112, base, oim, off, addr_rev, G, s);
    subB<MIRB>(S0, 120, base, oim, off, addr_rev, G, s);
  }
}

__global__ __launch_bounds__(128) void pool255_half(
    const float* __restrict__ x, float* __restrict__ out) {
  __shared__ float2 carry[2][3][64];  // 3 KB
  const int img = blockIdx.x;
  const float* __restrict__ xim = x + (size_t)img * NPIX;
  float* __restrict__ oim = out + (size_t)img * NPIX;
  const int l = threadIdx.x & 63;
  if (threadIdx.x < 64)
    wave_run<false>(xim, oim, carry, l);  // rows 0..63, TD first
  else
    wave_run<true>(xim, oim, carry, l);   // rows 64..127, BU first
}

extern "C" void kernel_launch(void* const* d_in, const int* in_sizes, int n_in,
                              void* d_out, int out_size, void* d_ws,
                              size_t ws_size, hipStream_t stream) {
  const float* x = (const float*)d_in[0];
  float* out = (float*)d_out;
  const int n_img = in_sizes[0] / NPIX;  // 8*256 = 2048
  pool255_half<<<n_img, 128, 0, stream>>>(x, out);
}

// Round 12
// 75.647 us; speedup vs baseline: 5.1513x; 1.5362x over previous
//
#include <hip/hip_runtime.h>

// Pool255: out = (1/8) * sum of 8 directional cumulative-max pools.
// x: [8,256,128,128] fp32. 2048 independent blocks (2 waves), 1 image each.
//
// Wave0 sweeps rows top-down computing dirs {(-1,0),(-1,-1),(-1,+1),(0,-1)};
// wave1 sweeps bottom-up in a COLUMN-MIRRORED view (lane l <-> col 127-2l),
// which turns its 4 dirs {(1,0),(1,1),(1,-1),(0,1)} into the SAME recurrences.
// Lane l owns 2 adjacent (view-)columns {2l,2l+1}. All shift-by-1 cross-lane
// ops are DPP wave_shr:1/wave_shl:1 (pure VALU, NEGF boundary via `old`).
// Phase 0 writes fp16x2 partials to LDS; lgkm-only barrier; phase 1 combines
// with the other wave's partial and NT-stores out.
//
// R12 vs R8: independent 2048-block grid (1 image/block, no grid-stride).
// 32 KB LDS = exactly 5 blocks/CU; the HW scheduler backfills finished
// blocks, keeping residency at 5/CU (10 waves) vs grid-stride's locked 4/CU.
// Body identical to R8: depth-8 prefetch ring crossing the lgkm-only
// barrier, Q[8] LDS prefetch, NT stores.

#define NPIX 16384
#define NEGF (-3.402823466e38f)

typedef __fp16 half2v __attribute__((ext_vector_type(2)));

// dst[l] = src[l -/+ 1]; invalid lanes get `oldv`.
template <int CTRL>
__device__ __forceinline__ float dpp_movf(float oldv, float src) {
  return __int_as_float(__builtin_amdgcn_update_dpp(
      __float_as_int(oldv), __float_as_int(src), CTRL, 0xf, 0xf, false));
}
#define WAVE_SHR1 0x138  // lane l reads lane l-1 (lane 0 -> old)
#define WAVE_SHL1 0x130  // lane l reads lane l+1 (lane 63 -> old)

// y = max(y, dpp_move(y)) ; masked/invalid lanes keep old=y (no-op)
#define DPP_MAXSTEP(y, ctrl, rmask)                                          \
  y = fmaxf(y, __int_as_float(__builtin_amdgcn_update_dpp(                   \
                 __float_as_int(y), __float_as_int(y), ctrl, rmask, 0xf,     \
                 false)))

// Barrier draining only LDS (lgkm) — global prefetches stay in flight.
__device__ __forceinline__ void lds_barrier() {
  asm volatile("s_waitcnt lgkmcnt(0)\n\ts_barrier" ::: "memory");
}

template <bool MIR>
__device__ __forceinline__ void run(const float* __restrict__ xim,
                                    float* __restrict__ oim,
                                    unsigned* __restrict__ part, const int l) {
  const int off = MIR ? (63 - l) * 2 : l * 2;  // float index of the col pair
  const int slot = MIR ? (63 - l) : l;         // u32 slot in a part row

  float v0 = NEGF, v1 = NEGF, d0 = NEGF, d1 = NEGF, a0 = NEGF, a1 = NEGF;

  // depth-8 x-load pipeline
  float2 G[8];
#pragma unroll
  for (int k = 0; k < 8; ++k) {
    const int row = MIR ? 127 - k : k;
    G[k] = *(const float2*)(xim + (row << 7) + off);
  }

  // ---- phase 0: t = 0..63, write fp16x2 partial to LDS ----
  for (int tb = 0; tb < 64; tb += 8) {
#pragma unroll
    for (int k = 0; k < 8; ++k) {
      const int t = tb + k;
      const float2 xv = G[k];
      const int pr = t + 8;  // 8..71: tail pre-issues phase-1 x rows
      const int prow = MIR ? 127 - pr : pr;
      G[k] = *(const float2*)(xim + (prow << 7) + off);

      const float x0 = MIR ? xv.y : xv.x;
      const float x1 = MIR ? xv.x : xv.y;

      v0 = fmaxf(v0, x0);
      v1 = fmaxf(v1, x1);

      // diagonal: D[c] = max(x[c], Dprev[c-1])
      const float pd = dpp_movf<WAVE_SHR1>(NEGF, d1);
      const float nd0 = fmaxf(x0, pd);
      const float nd1 = fmaxf(x1, d0);
      d0 = nd0; d1 = nd1;

      // anti-diagonal: A[c] = max(x[c], Aprev[c+1])
      const float pa = dpp_movf<WAVE_SHL1>(NEGF, a0);
      const float na1 = fmaxf(x1, pa);
      const float na0 = fmaxf(x0, a1);
      a0 = na0; a1 = na1;

      // row inclusive prefix-max over lane totals (DPP scan)
      float y = fmaxf(x0, x1);
      DPP_MAXSTEP(y, 0x111, 0xf);  // row_shr:1
      DPP_MAXSTEP(y, 0x112, 0xf);  // row_shr:2
      DPP_MAXSTEP(y, 0x114, 0xf);  // row_shr:4
      DPP_MAXSTEP(y, 0x118, 0xf);  // row_shr:8
      DPP_MAXSTEP(y, 0x142, 0xa);  // row_bcast15 -> rows 1,3
      DPP_MAXSTEP(y, 0x143, 0xc);  // row_bcast31 -> rows 2,3
      const float ex = dpp_movf<WAVE_SHR1>(NEGF, y);
      const float s0 = fmaxf(ex, x0);

      const float p0 = (v0 + d0) + (a0 + s0);
      const float p1 = (v1 + d1) + (a1 + y);

      const int row = MIR ? 127 - t : t;
      const half2v h = MIR ? __builtin_amdgcn_cvt_pkrtz(p1, p0)
                           : __builtin_amdgcn_cvt_pkrtz(p0, p1);
      part[(row << 6) + slot] = __builtin_bit_cast(unsigned, h);
    }
  }

  lds_barrier();  // partials visible; global prefetches stay in flight

  // ---- phase 1: t = 64..127, combine + store final float2 ----
  {
    unsigned Q[8];  // depth-8 LDS partial pipeline
#pragma unroll
    for (int k = 0; k < 8; ++k) {
      const int row = MIR ? 127 - (64 + k) : (64 + k);
      Q[k] = part[(row << 6) + slot];
    }
    for (int tb = 64; tb < 128; tb += 8) {
#pragma unroll
      for (int k = 0; k < 8; ++k) {
        const int t = tb + k;
        const float2 xv = G[k];
        const int pr = (t + 8 < 128) ? t + 8 : 127;  // clamp (uniform)
        const int prow = MIR ? 127 - pr : pr;
        G[k] = *(const float2*)(xim + (prow << 7) + off);

        const unsigned q = Q[k];
        Q[k] = part[(prow << 6) + slot];  // prefetch partial row t+8

        const float x0 = MIR ? xv.y : xv.x;
        const float x1 = MIR ? xv.x : xv.y;

        v0 = fmaxf(v0, x0);
        v1 = fmaxf(v1, x1);

        const float pd = dpp_movf<WAVE_SHR1>(NEGF, d1);
        const float nd0 = fmaxf(x0, pd);
        const float nd1 = fmaxf(x1, d0);
        d0 = nd0; d1 = nd1;

        const float pa = dpp_movf<WAVE_SHL1>(NEGF, a0);
        const float na1 = fmaxf(x1, pa);
        const float na0 = fmaxf(x0, a1);
        a0 = na0; a1 = na1;

        float y = fmaxf(x0, x1);
        DPP_MAXSTEP(y, 0x111, 0xf);
        DPP_MAXSTEP(y, 0x112, 0xf);
        DPP_MAXSTEP(y, 0x114, 0xf);
        DPP_MAXSTEP(y, 0x118, 0xf);
        DPP_MAXSTEP(y, 0x142, 0xa);
        DPP_MAXSTEP(y, 0x143, 0xc);
        const float ex = dpp_movf<WAVE_SHR1>(NEGF, y);
        const float s0 = fmaxf(ex, x0);

        const float p0 = (v0 + d0) + (a0 + s0);
        const float p1 = (v1 + d1) + (a1 + y);

        const half2v hq = __builtin_bit_cast(half2v, q);
        const float q0 = (float)(MIR ? hq.y : hq.x);
        const float q1 = (float)(MIR ? hq.x : hq.y);
        const float o0 = (p0 + q0) * 0.125f;
        const float o1 = (p1 + q1) * 0.125f;

        const int row = MIR ? 127 - t : t;
        const float2 ov = MIR ? make_float2(o1, o0) : make_float2(o0, o1);
        // nontemporal: streaming output, don't evict x from L2
        __builtin_nontemporal_store(
            __builtin_bit_cast(unsigned long long, ov),
            (unsigned long long*)(oim + (row << 7) + off));
      }
    }
  }
}

__global__ __launch_bounds__(128) void pool255_sweep(
    const float* __restrict__ x, float* __restrict__ out) {
  __shared__ unsigned part[NPIX / 2];  // fp16x2, 32 KB -> 5 blocks/CU
  const int img = blockIdx.x;
  const float* __restrict__ xim = x + (size_t)img * NPIX;
  float* __restrict__ oim = out + (size_t)img * NPIX;
  const int l = threadIdx.x & 63;
  if (threadIdx.x < 64)
    run<false>(xim, oim, part, l);
  else
    run<true>(xim, oim, part, l);
}

extern "C" void kernel_launch(void* const* d_in, const int* in_sizes, int n_in,
                              void* d_out, int out_size, void* d_ws,
                              size_t ws_size, hipStream_t stream) {
  const float* x = (const float*)d_in[0];
  float* out = (float*)d_out;
  const int n_img = in_sizes[0] / NPIX;  // 8*256 = 2048
  pool255_sweep<<<n_img, 128, 0, stream>>>(x, out);
}